// Round 1
// baseline (676.920 us; speedup 1.0000x reference)
//
#include <hip/hip_runtime.h>

typedef __bf16 bf16x8 __attribute__((ext_vector_type(8)));
typedef float f32x4 __attribute__((ext_vector_type(4)));

__device__ __forceinline__ f32x4 mfma16(bf16x8 a, bf16x8 b, f32x4 c) {
  return __builtin_amdgcn_mfma_f32_16x16x32_bf16(a, b, c, 0, 0, 0);
}

__device__ __forceinline__ bf16x8 cvt8(float4 a, float4 b) {
  bf16x8 h;
  h[0] = (__bf16)a.x; h[1] = (__bf16)a.y; h[2] = (__bf16)a.z; h[3] = (__bf16)a.w;
  h[4] = (__bf16)b.x; h[5] = (__bf16)b.y; h[6] = (__bf16)b.z; h[7] = (__bf16)b.w;
  return h;
}

// ---------------------------------------------------------------------------
// Kernel 1: projection GEMM (NT): O[m][n] = (sum_k A[m][k]*W[n][k] + bias[n])*scale
// A: f32 [8192][1024], W: f32 [1024][1024] (row-major [n][k]) -> bf16 out.
// OUT_MODE 0: row-major [8192][1024].  OUT_MODE 1: vpT layout [B][H][D][S].
// ---------------------------------------------------------------------------
template<int OUT_MODE>
__global__ __launch_bounds__(256, 2)
void proj_gemm(const float* __restrict__ A, const float* __restrict__ W,
               const float* __restrict__ bias, __bf16* __restrict__ O, float scale)
{
  constexpr int LDT = 40;  // padded bf16 stride (80B rows) to break LDS bank conflicts
  __shared__ __align__(16) __bf16 lA[128 * LDT];
  __shared__ __align__(16) __bf16 lB[128 * LDT];
  const int tid = threadIdx.x;
  const int lane = tid & 63;
  const int wid = tid >> 6;
  const int bn0 = blockIdx.x * 128;
  const int bm0 = blockIdx.y * 128;
  const int wm = (wid >> 1) * 64;
  const int wn = (wid & 1) * 64;
  const int lr = lane & 15;
  const int lk = (lane >> 4) * 8;

  f32x4 acc[4][4];
  #pragma unroll
  for (int i = 0; i < 4; ++i)
    #pragma unroll
    for (int j = 0; j < 4; ++j) acc[i][j] = (f32x4){0.f, 0.f, 0.f, 0.f};

  const int rs = tid >> 2;        // 0..63
  const int cs = (tid & 3) * 8;   // 0,8,16,24

  for (int k0 = 0; k0 < 1024; k0 += 32) {
    #pragma unroll
    for (int rr = 0; rr < 2; ++rr) {
      const int r = rs + rr * 64;
      const float* sa = A + (size_t)(bm0 + r) * 1024 + k0 + cs;
      const float* sb = W + (size_t)(bn0 + r) * 1024 + k0 + cs;
      float4 a0 = *(const float4*)sa;
      float4 a1 = *(const float4*)(sa + 4);
      float4 b0 = *(const float4*)sb;
      float4 b1 = *(const float4*)(sb + 4);
      *(bf16x8*)&lA[r * LDT + cs] = cvt8(a0, a1);
      *(bf16x8*)&lB[r * LDT + cs] = cvt8(b0, b1);
    }
    __syncthreads();
    bf16x8 aF[4], bF[4];
    #pragma unroll
    for (int t = 0; t < 4; ++t) {
      aF[t] = *(const bf16x8*)&lA[(wm + t * 16 + lr) * LDT + lk];
      bF[t] = *(const bf16x8*)&lB[(wn + t * 16 + lr) * LDT + lk];
    }
    #pragma unroll
    for (int mt = 0; mt < 4; ++mt)
      #pragma unroll
      for (int nt = 0; nt < 4; ++nt)
        acc[mt][nt] = mfma16(aF[mt], bF[nt], acc[mt][nt]);
    __syncthreads();
  }

  const int col = lane & 15;
  const int rb = (lane >> 4) * 4;
  #pragma unroll
  for (int nt = 0; nt < 4; ++nt) {
    const int n = bn0 + wn + nt * 16 + col;
    const float bvv = bias[n];
    #pragma unroll
    for (int mt = 0; mt < 4; ++mt) {
      #pragma unroll
      for (int i = 0; i < 4; ++i) {
        const int m = bm0 + wm + mt * 16 + rb + i;
        const float v = (acc[mt][nt][i] + bvv) * scale;
        if constexpr (OUT_MODE == 0) {
          O[(size_t)m * 1024 + n] = (__bf16)v;
        } else {
          // vpT[b][h][d][s]: b=m>>10, s=m&1023, h=n>>6, d=n&63
          const int bb = m >> 10, s = m & 1023, hh = n >> 6, dd = n & 63;
          O[((size_t)((bb * 16 + hh) * 64 + dd)) * 1024 + s] = (__bf16)v;
        }
      }
    }
  }
}

// ---------------------------------------------------------------------------
// Kernel 2: attention. One block per (b, 16-row t-tile); loops all 16 heads.
// scores f32 [16][1024] in LDS, P bf16 (swizzled) [16][1024], running head-max
// bf16 [16][1024]. Softmax 1/l folded into PV epilogue.
// ---------------------------------------------------------------------------
__global__ __launch_bounds__(256, 1)
void attn_kernel(const __bf16* __restrict__ qp, const __bf16* __restrict__ kp,
                 const __bf16* __restrict__ vpT, __bf16* __restrict__ rep,
                 float* __restrict__ amax_out)
{
  __shared__ __align__(16) float sc[16 * 1024];     // 64KB
  __shared__ __align__(16) __bf16 pb[16 * 1024];    // 32KB
  __shared__ __align__(16) __bf16 amaxb[16 * 1024]; // 32KB
  __shared__ float rowinv[16];

  const int bid = blockIdx.x;
  const int b = bid & 7;          // same-b blocks land on same XCD (L2 reuse of kp/vpT)
  const int t0 = (bid >> 3) * 16;
  const int tid = threadIdx.x;
  const int lane = tid & 63;
  const int w = tid >> 6;
  const int lr = lane & 15;
  const int lk = (lane >> 4) * 8;
  const int rb = (lane >> 4) * 4;
  const int row = tid >> 4;  // 0..15
  const int g = tid & 15;

  for (int h = 0; h < 16; ++h) {
    // ---- scores: sc[r][s] = sum_d q[t0+r][h*64+d] * k[s][h*64+d] ----
    const __bf16* qb = qp + (size_t)(b * 1024 + t0 + lr) * 1024 + h * 64 + lk;
    const bf16x8 aF0 = *(const bf16x8*)qb;
    const bf16x8 aF1 = *(const bf16x8*)(qb + 32);
    #pragma unroll 4
    for (int j = 0; j < 16; ++j) {
      const int st = w * 16 + j;
      const __bf16* kb = kp + (size_t)(b * 1024 + st * 16 + lr) * 1024 + h * 64 + lk;
      const bf16x8 bF0 = *(const bf16x8*)kb;
      const bf16x8 bF1 = *(const bf16x8*)(kb + 32);
      f32x4 d = {0.f, 0.f, 0.f, 0.f};
      d = mfma16(aF0, bF0, d);
      d = mfma16(aF1, bF1, d);
      #pragma unroll
      for (int i = 0; i < 4; ++i) sc[(rb + i) * 1024 + st * 16 + (lane & 15)] = d[i];
    }
    __syncthreads();

    // ---- softmax (16 threads per row; elements strided 16) ----
    float* srow = sc + row * 1024;
    float mx = -3.0e38f;
    #pragma unroll 8
    for (int e = 0; e < 64; ++e) mx = fmaxf(mx, srow[g + (e << 4)]);
    #pragma unroll
    for (int off = 8; off; off >>= 1) mx = fmaxf(mx, __shfl_xor(mx, off, 16));
    float sum = 0.f;
    #pragma unroll 8
    for (int e = 0; e < 64; ++e) {
      const int idx = g + (e << 4);
      const float p = __expf(srow[idx] - mx);
      sum += p;
      srow[idx] = p;  // unnormalized prob, f32
      // swizzled bf16 store for conflict-reduced ds_read_b128 in PV
      *(__bf16*)((char*)pb + row * 2048 + (((unsigned)(idx * 2)) ^ ((unsigned)((row & 7) << 4)))) = (__bf16)p;
    }
    #pragma unroll
    for (int off = 8; off; off >>= 1) sum += __shfl_xor(sum, off, 16);
    const float inv = 1.f / sum;
    if (g == 0) rowinv[row] = inv;
    // ---- running max over heads of normalized probs ----
    if (h == 0) {
      #pragma unroll 8
      for (int e = 0; e < 64; ++e) {
        const int idx = g + (e << 4);
        amaxb[row * 1024 + idx] = (__bf16)(srow[idx] * inv);
      }
    } else {
      #pragma unroll 8
      for (int e = 0; e < 64; ++e) {
        const int idx = g + (e << 4);
        const float pn = srow[idx] * inv;
        const float o = (float)amaxb[row * 1024 + idx];
        if (pn > o) amaxb[row * 1024 + idx] = (__bf16)pn;
      }
    }
    __syncthreads();

    // ---- PV: rep[r][h*64 + w*16 + c] = inv_r * sum_s P[r][s] * v[s][d] ----
    f32x4 acc2 = {0.f, 0.f, 0.f, 0.f};
    const __bf16* vb = vpT + ((size_t)(b * 16 + h) * 64 + w * 16 + lr) * 1024;
    #pragma unroll 8
    for (int kk = 0; kk < 32; ++kk) {
      const int kofs = kk * 32 + lk;
      const bf16x8 aP = *(const bf16x8*)((const char*)pb + lr * 2048 +
                          (((unsigned)(kofs * 2)) ^ ((unsigned)((lr & 7) << 4))));
      const bf16x8 bV = *(const bf16x8*)(vb + kofs);
      acc2 = mfma16(aP, bV, acc2);
    }
    #pragma unroll
    for (int i = 0; i < 4; ++i) {
      const float rv = acc2[i] * rowinv[rb + i];
      rep[(size_t)(b * 1024 + t0 + rb + i) * 1024 + h * 64 + w * 16 + (lane & 15)] = (__bf16)rv;
    }
    __syncthreads();
  }

  // ---- write attn_max (f32) ----
  float* aout = amax_out + (size_t)(b * 1024 + t0) * 1024;
  for (int i = tid; i < 16 * 1024; i += 256) aout[i] = (float)amaxb[i];
}

// ---------------------------------------------------------------------------
// Kernel 3: out projection: O[m][n] = sum_k rep[m][k]*Wo[n][k] + bo[n]  (f32 out)
// ---------------------------------------------------------------------------
__global__ __launch_bounds__(256, 2)
void out_gemm(const __bf16* __restrict__ A, const float* __restrict__ W,
              const float* __restrict__ bias, float* __restrict__ O)
{
  constexpr int LDT = 40;
  __shared__ __align__(16) __bf16 lA[128 * LDT];
  __shared__ __align__(16) __bf16 lB[128 * LDT];
  const int tid = threadIdx.x;
  const int lane = tid & 63;
  const int wid = tid >> 6;
  const int bn0 = blockIdx.x * 128;
  const int bm0 = blockIdx.y * 128;
  const int wm = (wid >> 1) * 64;
  const int wn = (wid & 1) * 64;
  const int lr = lane & 15;
  const int lk = (lane >> 4) * 8;

  f32x4 acc[4][4];
  #pragma unroll
  for (int i = 0; i < 4; ++i)
    #pragma unroll
    for (int j = 0; j < 4; ++j) acc[i][j] = (f32x4){0.f, 0.f, 0.f, 0.f};

  const int rs = tid >> 2;
  const int cs = (tid & 3) * 8;

  for (int k0 = 0; k0 < 1024; k0 += 32) {
    #pragma unroll
    for (int rr = 0; rr < 2; ++rr) {
      const int r = rs + rr * 64;
      const bf16x8 av = *(const bf16x8*)(A + (size_t)(bm0 + r) * 1024 + k0 + cs);
      const float* sb = W + (size_t)(bn0 + r) * 1024 + k0 + cs;
      float4 b0 = *(const float4*)sb;
      float4 b1 = *(const float4*)(sb + 4);
      *(bf16x8*)&lA[r * LDT + cs] = av;
      *(bf16x8*)&lB[r * LDT + cs] = cvt8(b0, b1);
    }
    __syncthreads();
    bf16x8 aF[4], bF[4];
    #pragma unroll
    for (int t = 0; t < 4; ++t) {
      aF[t] = *(const bf16x8*)&lA[(wm + t * 16 + lr) * LDT + lk];
      bF[t] = *(const bf16x8*)&lB[(wn + t * 16 + lr) * LDT + lk];
    }
    #pragma unroll
    for (int mt = 0; mt < 4; ++mt)
      #pragma unroll
      for (int nt = 0; nt < 4; ++nt)
        acc[mt][nt] = mfma16(aF[mt], bF[nt], acc[mt][nt]);
    __syncthreads();
  }

  const int col = lane & 15;
  const int rb = (lane >> 4) * 4;
  #pragma unroll
  for (int nt = 0; nt < 4; ++nt) {
    const int n = bn0 + wn + nt * 16 + col;
    const float bvv = bias[n];
    #pragma unroll
    for (int mt = 0; mt < 4; ++mt) {
      #pragma unroll
      for (int i = 0; i < 4; ++i) {
        const int m = bm0 + wm + mt * 16 + rb + i;
        O[(size_t)m * 1024 + n] = acc[mt][nt][i] + bvv;
      }
    }
  }
}

// ---------------------------------------------------------------------------
extern "C" void kernel_launch(void* const* d_in, const int* in_sizes, int n_in,
                              void* d_out, int out_size, void* d_ws, size_t ws_size,
                              hipStream_t stream)
{
  const float* query = (const float*)d_in[0];
  const float* key   = (const float*)d_in[1];
  const float* value = (const float*)d_in[2];
  const float* Wq = (const float*)d_in[3];
  const float* bq = (const float*)d_in[4];
  const float* Wk = (const float*)d_in[5];
  const float* bk = (const float*)d_in[6];
  const float* Wv = (const float*)d_in[7];
  const float* bv = (const float*)d_in[8];
  const float* Wo = (const float*)d_in[9];
  const float* bo = (const float*)d_in[10];

  float* out = (float*)d_out;
  float* amax_out = out + (size_t)8 * 1024 * 1024;  // out is [8,1024,1024] f32 first

  char* wsb = (char*)d_ws;
  __bf16* qp  = (__bf16*)wsb;                                // 16MB
  __bf16* kp  = (__bf16*)(wsb + ((size_t)16 << 20));          // 16MB
  __bf16* vpT = (__bf16*)(wsb + ((size_t)32 << 20));          // 16MB [B][H][D][S]
  // rep: own slot if ws allows, else alias qp (safe: head h reads qp cols h*64
  // strictly before PV writes rep cols h*64; rows are block-exclusive).
  __bf16* rep = (ws_size >= ((size_t)64 << 20)) ? (__bf16*)(wsb + ((size_t)48 << 20)) : qp;

  dim3 gG(8, 64);
  proj_gemm<0><<<gG, 256, 0, stream>>>(query, Wq, bq, qp, 0.125f);  // D^-0.5 folded
  proj_gemm<0><<<gG, 256, 0, stream>>>(key,   Wk, bk, kp, 1.0f);
  proj_gemm<1><<<gG, 256, 0, stream>>>(value, Wv, bv, vpT, 1.0f);
  attn_kernel<<<512, 256, 0, stream>>>(qp, kp, vpT, rep, amax_out);
  out_gemm<<<gG, 256, 0, stream>>>(rep, Wo, bo, out);
}

// Round 2
// 442.795 us; speedup vs baseline: 1.5287x; 1.5287x over previous
//
#include <hip/hip_runtime.h>

typedef __bf16 bf16x8 __attribute__((ext_vector_type(8)));
typedef float f32x4 __attribute__((ext_vector_type(4)));

__device__ __forceinline__ f32x4 mfma16(bf16x8 a, bf16x8 b, f32x4 c) {
  return __builtin_amdgcn_mfma_f32_16x16x32_bf16(a, b, c, 0, 0, 0);
}

__device__ __forceinline__ bf16x8 cvt8(float4 a, float4 b) {
  bf16x8 h;
  h[0] = (__bf16)a.x; h[1] = (__bf16)a.y; h[2] = (__bf16)a.z; h[3] = (__bf16)a.w;
  h[4] = (__bf16)b.x; h[5] = (__bf16)b.y; h[6] = (__bf16)b.z; h[7] = (__bf16)b.w;
  return h;
}

// ---------------------------------------------------------------------------
// Kernel 1: projection GEMM (NT): O[m][n] = (sum_k A[m][k]*W[n][k] + bias[n])*scale
// A: f32 [8192][1024], W: f32 [1024][1024] (row-major [n][k]) -> bf16 out.
// OUT_MODE 0: row-major [8192][1024].  OUT_MODE 1: vpT layout [B][H][D][S].
// ---------------------------------------------------------------------------
template<int OUT_MODE>
__global__ __launch_bounds__(256, 2)
void proj_gemm(const float* __restrict__ A, const float* __restrict__ W,
               const float* __restrict__ bias, __bf16* __restrict__ O, float scale)
{
  constexpr int LDT = 40;  // padded bf16 stride (80B rows) to break LDS bank conflicts
  __shared__ __align__(16) __bf16 lA[128 * LDT];
  __shared__ __align__(16) __bf16 lB[128 * LDT];
  const int tid = threadIdx.x;
  const int lane = tid & 63;
  const int wid = tid >> 6;
  const int bn0 = blockIdx.x * 128;
  const int bm0 = blockIdx.y * 128;
  const int wm = (wid >> 1) * 64;
  const int wn = (wid & 1) * 64;
  const int lr = lane & 15;
  const int lk = (lane >> 4) * 8;

  f32x4 acc[4][4];
  #pragma unroll
  for (int i = 0; i < 4; ++i)
    #pragma unroll
    for (int j = 0; j < 4; ++j) acc[i][j] = (f32x4){0.f, 0.f, 0.f, 0.f};

  const int rs = tid >> 2;        // 0..63
  const int cs = (tid & 3) * 8;   // 0,8,16,24

  for (int k0 = 0; k0 < 1024; k0 += 32) {
    #pragma unroll
    for (int rr = 0; rr < 2; ++rr) {
      const int r = rs + rr * 64;
      const float* sa = A + (size_t)(bm0 + r) * 1024 + k0 + cs;
      const float* sb = W + (size_t)(bn0 + r) * 1024 + k0 + cs;
      float4 a0 = *(const float4*)sa;
      float4 a1 = *(const float4*)(sa + 4);
      float4 b0 = *(const float4*)sb;
      float4 b1 = *(const float4*)(sb + 4);
      *(bf16x8*)&lA[r * LDT + cs] = cvt8(a0, a1);
      *(bf16x8*)&lB[r * LDT + cs] = cvt8(b0, b1);
    }
    __syncthreads();
    bf16x8 aF[4], bF[4];
    #pragma unroll
    for (int t = 0; t < 4; ++t) {
      aF[t] = *(const bf16x8*)&lA[(wm + t * 16 + lr) * LDT + lk];
      bF[t] = *(const bf16x8*)&lB[(wn + t * 16 + lr) * LDT + lk];
    }
    #pragma unroll
    for (int mt = 0; mt < 4; ++mt)
      #pragma unroll
      for (int nt = 0; nt < 4; ++nt)
        acc[mt][nt] = mfma16(aF[mt], bF[nt], acc[mt][nt]);
    __syncthreads();
  }

  const int col = lane & 15;
  const int rb = (lane >> 4) * 4;
  #pragma unroll
  for (int nt = 0; nt < 4; ++nt) {
    const int n = bn0 + wn + nt * 16 + col;
    const float bvv = bias[n];
    #pragma unroll
    for (int mt = 0; mt < 4; ++mt) {
      #pragma unroll
      for (int i = 0; i < 4; ++i) {
        const int m = bm0 + wm + mt * 16 + rb + i;
        const float v = (acc[mt][nt][i] + bvv) * scale;
        if constexpr (OUT_MODE == 0) {
          O[(size_t)m * 1024 + n] = (__bf16)v;
        } else {
          // vpT[b][h][d][s]: b=m>>10, s=m&1023, h=n>>6, d=n&63
          const int bb = m >> 10, s = m & 1023, hh = n >> 6, dd = n & 63;
          O[((size_t)((bb * 16 + hh) * 64 + dd)) * 1024 + s] = (__bf16)v;
        }
      }
    }
  }
}

// ---------------------------------------------------------------------------
// Kernel 2: attention, register-resident softmax.
// One block per (b, 16-row t-tile); loops 16 heads. Scores live in MFMA
// accumulators (p[16] f32x4 per lane); row max/sum via in-register reduce +
// shfl_xor within 16-lane group + tiny cross-wave LDS reduce (2 barriers/head).
// P staged once to swizzled bf16 LDS (double-buffered) for the PV A-fragment.
// Running attn_max over heads kept in registers, written once at the end.
// ---------------------------------------------------------------------------
__global__ __launch_bounds__(256, 2)
void attn_kernel(const __bf16* __restrict__ qp, const __bf16* __restrict__ kp,
                 const __bf16* __restrict__ vpT, __bf16* __restrict__ rep,
                 float* __restrict__ amax_out)
{
  __shared__ __align__(16) __bf16 pb[2][16 * 1024];  // 64KB double-buffered P
  __shared__ float redm[4 * 16];
  __shared__ float reds[4 * 16];

  const int bid = blockIdx.x;
  const int b = bid & 7;          // same-b blocks -> same XCD (L2 reuse of kp/vpT)
  const int t0 = (bid >> 3) * 16;
  const int tid = threadIdx.x;
  const int lane = tid & 63;
  const int w = tid >> 6;         // wave: owns s-range [w*256, w*256+256)
  const int lr = lane & 15;
  const int lk = (lane >> 4) * 8;
  const int rb = (lane >> 4) * 4;

  f32x4 am[16];                   // running max over heads of normalized probs
  #pragma unroll
  for (int j = 0; j < 16; ++j) am[j] = (f32x4){0.f, 0.f, 0.f, 0.f};

  for (int h = 0; h < 16; ++h) {
    // ---- QK^T into registers: p[j][i] = score[row rb+i][col (w*16+j)*16+lr] ----
    const __bf16* qb = qp + (size_t)(b * 1024 + t0 + lr) * 1024 + h * 64 + lk;
    const bf16x8 aF0 = *(const bf16x8*)qb;
    const bf16x8 aF1 = *(const bf16x8*)(qb + 32);
    f32x4 p[16];
    #pragma unroll
    for (int j = 0; j < 16; ++j) {
      const int st = w * 16 + j;
      const __bf16* kb = kp + (size_t)(b * 1024 + st * 16 + lr) * 1024 + h * 64 + lk;
      const bf16x8 bF0 = *(const bf16x8*)kb;
      const bf16x8 bF1 = *(const bf16x8*)(kb + 32);
      f32x4 d = {0.f, 0.f, 0.f, 0.f};
      d = mfma16(aF0, bF0, d);
      d = mfma16(aF1, bF1, d);
      p[j] = d;
    }

    // ---- row max: registers -> 16-lane shuffle -> cross-wave LDS ----
    f32x4 m = p[0];
    #pragma unroll
    for (int j = 1; j < 16; ++j)
      #pragma unroll
      for (int i = 0; i < 4; ++i) m[i] = fmaxf(m[i], p[j][i]);
    #pragma unroll
    for (int off = 1; off < 16; off <<= 1)
      #pragma unroll
      for (int i = 0; i < 4; ++i) m[i] = fmaxf(m[i], __shfl_xor(m[i], off));
    if (lr == 0) {
      #pragma unroll
      for (int i = 0; i < 4; ++i) redm[w * 16 + rb + i] = m[i];
    }
    __syncthreads();  // B1
    f32x4 mx;
    #pragma unroll
    for (int i = 0; i < 4; ++i)
      mx[i] = fmaxf(fmaxf(redm[rb + i], redm[16 + rb + i]),
                    fmaxf(redm[32 + rb + i], redm[48 + rb + i]));

    // ---- exp + sum in registers; single swizzled bf16 store of P ----
    __bf16* pbh = pb[h & 1];
    f32x4 s = (f32x4){0.f, 0.f, 0.f, 0.f};
    #pragma unroll
    for (int j = 0; j < 16; ++j) {
      const int cb2 = ((w * 16 + j) * 16 + lr) * 2;  // byte col offset
      #pragma unroll
      for (int i = 0; i < 4; ++i) {
        const float e = __expf(p[j][i] - mx[i]);
        p[j][i] = e;
        s[i] += e;
        const int row = rb + i;
        *(__bf16*)((char*)pbh + row * 2048 +
                   ((unsigned)cb2 ^ ((unsigned)((row & 7) << 4)))) = (__bf16)e;
      }
    }
    #pragma unroll
    for (int off = 1; off < 16; off <<= 1)
      #pragma unroll
      for (int i = 0; i < 4; ++i) s[i] += __shfl_xor(s[i], off);
    if (lr == 0) {
      #pragma unroll
      for (int i = 0; i < 4; ++i) reds[w * 16 + rb + i] = s[i];
    }
    __syncthreads();  // B2 (also covers P stores before PV reads)
    f32x4 inv;
    #pragma unroll
    for (int i = 0; i < 4; ++i)
      inv[i] = 1.f / (reds[rb + i] + reds[16 + rb + i] +
                      reds[32 + rb + i] + reds[48 + rb + i]);

    // ---- running attn_max in registers ----
    #pragma unroll
    for (int j = 0; j < 16; ++j)
      #pragma unroll
      for (int i = 0; i < 4; ++i) am[j][i] = fmaxf(am[j][i], p[j][i] * inv[i]);

    // ---- PV: rep[row][h*64 + w*16 + c] = inv * sum_s P[row][s] * v[s][d] ----
    f32x4 acc2 = (f32x4){0.f, 0.f, 0.f, 0.f};
    const __bf16* vb = vpT + ((size_t)(b * 16 + h) * 64 + w * 16 + lr) * 1024;
    #pragma unroll 8
    for (int kk = 0; kk < 32; ++kk) {
      const int kofs = kk * 32 + lk;
      const bf16x8 aP = *(const bf16x8*)((const char*)pbh + lr * 2048 +
                          ((unsigned)(kofs * 2) ^ ((unsigned)((lr & 7) << 4))));
      const bf16x8 bV = *(const bf16x8*)(vb + kofs);
      acc2 = mfma16(aP, bV, acc2);
    }
    #pragma unroll
    for (int i = 0; i < 4; ++i)
      rep[(size_t)(b * 1024 + t0 + rb + i) * 1024 + h * 64 + w * 16 + lr] =
          (__bf16)(acc2[i] * inv[i]);
    // no barrier needed here: pb is double-buffered and B1/B2 of the next head
    // prevent any wave from getting a full head ahead.
  }

  // ---- write attn_max from registers ----
  #pragma unroll
  for (int j = 0; j < 16; ++j) {
    const int c = (w * 16 + j) * 16 + lr;
    #pragma unroll
    for (int i = 0; i < 4; ++i)
      amax_out[(size_t)(b * 1024 + t0 + rb + i) * 1024 + c] = am[j][i];
  }
}

// ---------------------------------------------------------------------------
// Kernel 3: out projection: O[m][n] = sum_k rep[m][k]*Wo[n][k] + bo[n]  (f32 out)
// ---------------------------------------------------------------------------
__global__ __launch_bounds__(256, 2)
void out_gemm(const __bf16* __restrict__ A, const float* __restrict__ W,
              const float* __restrict__ bias, float* __restrict__ O)
{
  constexpr int LDT = 40;
  __shared__ __align__(16) __bf16 lA[128 * LDT];
  __shared__ __align__(16) __bf16 lB[128 * LDT];
  const int tid = threadIdx.x;
  const int lane = tid & 63;
  const int wid = tid >> 6;
  const int bn0 = blockIdx.x * 128;
  const int bm0 = blockIdx.y * 128;
  const int wm = (wid >> 1) * 64;
  const int wn = (wid & 1) * 64;
  const int lr = lane & 15;
  const int lk = (lane >> 4) * 8;

  f32x4 acc[4][4];
  #pragma unroll
  for (int i = 0; i < 4; ++i)
    #pragma unroll
    for (int j = 0; j < 4; ++j) acc[i][j] = (f32x4){0.f, 0.f, 0.f, 0.f};

  const int rs = tid >> 2;
  const int cs = (tid & 3) * 8;

  for (int k0 = 0; k0 < 1024; k0 += 32) {
    #pragma unroll
    for (int rr = 0; rr < 2; ++rr) {
      const int r = rs + rr * 64;
      const bf16x8 av = *(const bf16x8*)(A + (size_t)(bm0 + r) * 1024 + k0 + cs);
      const float* sb = W + (size_t)(bn0 + r) * 1024 + k0 + cs;
      float4 b0 = *(const float4*)sb;
      float4 b1 = *(const float4*)(sb + 4);
      *(bf16x8*)&lA[r * LDT + cs] = av;
      *(bf16x8*)&lB[r * LDT + cs] = cvt8(b0, b1);
    }
    __syncthreads();
    bf16x8 aF[4], bF[4];
    #pragma unroll
    for (int t = 0; t < 4; ++t) {
      aF[t] = *(const bf16x8*)&lA[(wm + t * 16 + lr) * LDT + lk];
      bF[t] = *(const bf16x8*)&lB[(wn + t * 16 + lr) * LDT + lk];
    }
    #pragma unroll
    for (int mt = 0; mt < 4; ++mt)
      #pragma unroll
      for (int nt = 0; nt < 4; ++nt)
        acc[mt][nt] = mfma16(aF[mt], bF[nt], acc[mt][nt]);
    __syncthreads();
  }

  const int col = lane & 15;
  const int rb = (lane >> 4) * 4;
  #pragma unroll
  for (int nt = 0; nt < 4; ++nt) {
    const int n = bn0 + wn + nt * 16 + col;
    const float bvv = bias[n];
    #pragma unroll
    for (int mt = 0; mt < 4; ++mt) {
      #pragma unroll
      for (int i = 0; i < 4; ++i) {
        const int m = bm0 + wm + mt * 16 + rb + i;
        O[(size_t)m * 1024 + n] = acc[mt][nt][i] + bvv;
      }
    }
  }
}

// ---------------------------------------------------------------------------
extern "C" void kernel_launch(void* const* d_in, const int* in_sizes, int n_in,
                              void* d_out, int out_size, void* d_ws, size_t ws_size,
                              hipStream_t stream)
{
  const float* query = (const float*)d_in[0];
  const float* key   = (const float*)d_in[1];
  const float* value = (const float*)d_in[2];
  const float* Wq = (const float*)d_in[3];
  const float* bq = (const float*)d_in[4];
  const float* Wk = (const float*)d_in[5];
  const float* bk = (const float*)d_in[6];
  const float* Wv = (const float*)d_in[7];
  const float* bv = (const float*)d_in[8];
  const float* Wo = (const float*)d_in[9];
  const float* bo = (const float*)d_in[10];

  float* out = (float*)d_out;
  float* amax_out = out + (size_t)8 * 1024 * 1024;  // out is [8,1024,1024] f32 first

  char* wsb = (char*)d_ws;
  __bf16* qp  = (__bf16*)wsb;                                 // 16MB
  __bf16* kp  = (__bf16*)(wsb + ((size_t)16 << 20));          // 16MB
  __bf16* vpT = (__bf16*)(wsb + ((size_t)32 << 20));          // 16MB [B][H][D][S]
  // rep: own slot if ws allows, else alias qp (safe: head h reads qp cols h*64
  // strictly before PV writes rep cols h*64; rows are block-exclusive).
  __bf16* rep = (ws_size >= ((size_t)64 << 20)) ? (__bf16*)(wsb + ((size_t)48 << 20)) : qp;

  dim3 gG(8, 64);
  proj_gemm<0><<<gG, 256, 0, stream>>>(query, Wq, bq, qp, 0.125f);  // D^-0.5 folded
  proj_gemm<0><<<gG, 256, 0, stream>>>(key,   Wk, bk, kp, 1.0f);
  proj_gemm<1><<<gG, 256, 0, stream>>>(value, Wv, bv, vpT, 1.0f);
  attn_kernel<<<512, 256, 0, stream>>>(qp, kp, vpT, rep, amax_out);
  out_gemm<<<gG, 256, 0, stream>>>(rep, Wo, bo, out);
}